// Round 6
// baseline (466.129 us; speedup 1.0000x reference)
//
#include <hip/hip_runtime.h>
#include <cmath>

#define NA 3
#define HSIZE 8192
#define HMASK (HSIZE - 1)

typedef float v4f __attribute__((ext_vector_type(4)));

// ws layout:
//   0:      double sums[16]     [0]=nb_dense [1]=conf_dense [2]=c50_dense
//                               [3]=excl_nb [4]=excl_conf [5]=excl_cnt
//                               [6..9]=lx,ly,lw,lh [10]=bce_obj [11]=conf_obj
//                               [12]=i50det [13]=i75det [14]=n_obj
//   128:    int A_key[8192]  A_val[8192]  B_key[8192]  B_bits[8192]  B_maxt[8192]
//   then:   int ocell[T]  keyarr[T]

__device__ __forceinline__ float sigf(float v){ return 1.0f/(1.0f + expf(-v)); }
// fast path: v_exp_f32 + v_rcp_f32 (~1ulp) — dense bulk only
__device__ __forceinline__ float fast_sig(float v){
  return __builtin_amdgcn_rcpf(1.0f + __expf(-v));
}
__device__ __forceinline__ unsigned hslot(unsigned key){
  return (key * 2654435761u) >> 19;   // top 13 bits -> [0, 8192)
}

__global__ __launch_bounds__(256) void k_zero(int* __restrict__ p, int n){
  int i = blockIdx.x*256 + threadIdx.x;
  if (i < n) p[i] = 0;
}

__global__ __launch_bounds__(256) void k_targets(
    const float* __restrict__ targets, int T, int G, float stride,
    int* __restrict__ ocell, int* __restrict__ keyarr,
    int* __restrict__ A_key, int* __restrict__ A_val,
    int* __restrict__ B_key, int* __restrict__ B_bits, int* __restrict__ B_maxt)
{
  int t = blockIdx.x*256 + threadIdx.x;
  if (t >= T) return;
  const float* tr = targets + (size_t)t*6;
  int b = (int)tr[0];
  float gx = tr[2]*(float)G, gy = tr[3]*(float)G, gw = tr[4]*(float)G, gh = tr[5]*(float)G;
  float aw[NA] = {116.0f/stride, 156.0f/stride, 373.0f/stride};
  float ah[NA] = { 90.0f/stride, 198.0f/stride, 326.0f/stride};
  float best_iou = -1.0f; int best = 0; int bits = 0;
  #pragma unroll
  for (int a = 0; a < NA; ++a){
    float inter = fminf(aw[a], gw) * fminf(ah[a], gh);
    float uni   = aw[a]*ah[a] + gw*gh - inter;
    float iou   = inter / (uni + 1e-16f);
    if (iou > best_iou){ best_iou = iou; best = a; }
    if (iou > 0.5f) bits |= (1 << a);
  }
  bits |= (1 << best);
  int gi = (int)floorf(gx); gi = gi < 0 ? 0 : (gi > G-1 ? G-1 : gi);
  int gj = (int)floorf(gy); gj = gj < 0 ? 0 : (gj > G-1 ? G-1 : gj);
  int cell = (b*G + gj)*G + gi;             // < 2^21
  int okey = cell*4 + best;
  ocell[t]  = okey;
  keyarr[t] = (cell << 3) | bits;

  // table A: (cell,best) -> max t (last target wins scatter semantics)
  unsigned s = hslot((unsigned)okey) & HMASK;
  for (;;){
    int prev = atomicCAS(&A_key[s], 0, okey+1);
    if (prev == 0 || prev == okey+1){ atomicMax(&A_val[s], t+1); break; }
    s = (s+1) & HMASK;
  }
  // table B: cell -> union of excluded anchor bits, representative = max t
  s = hslot((unsigned)cell) & HMASK;
  for (;;){
    int prev = atomicCAS(&B_key[s], 0, cell+1);
    if (prev == 0 || prev == cell+1){
      atomicOr(&B_bits[s], bits);
      atomicMax(&B_maxt[s], t+1);
      break;
    }
    s = (s+1) & HMASK;
  }
}

// Per-cell compute: all operands are named scalars / vector components,
// indices compile-time — nothing can be demoted to scratch.
#define DO_CELL(JV, P0, P1, P2, P3, P4, O0, O1, O2, O3, O4)        \
  {                                                                \
    float cx_   = fast_sig(P0);                                    \
    float cy_   = fast_sig(P1);                                    \
    float pw_   = __expf(P2)*aw;                                   \
    float ph_   = __expf(P3)*ah;                                   \
    float cf_   = fast_sig(P4);                                    \
    O0 = ((float)(gx + (JV)) + cx_)*stride;                        \
    O1 = ((float)gy + cy_)*stride;                                 \
    O2 = pw_*stride;                                               \
    O3 = ph_*stride;                                               \
    O4 = cf_;                                                      \
    nb -= __logf(1.0f - cf_ + 1e-12f);                             \
    cs += cf_;                                                     \
    c50 += (cf_ > 0.5f) ? 1 : 0;                                   \
  }

// Fused kernel:
//   blocks [0, nblkT)       : sparse per-target path (scheduled FIRST; its
//                             hash-probe/gather latency hides under dense work)
//   blocks [nblkT, nblkTot) : dense path, 8 cells/thread, NO LDS staging —
//                             named-register transpose into 10 v4f NT stores
//                             (160B/thread contiguous -> L2 write-combine).
// __launch_bounds__(256,4): guarantees 4 waves/EU (4 blocks/CU, 50% occ) and
// caps the allocator's occupancy ambition -> VGPR budget 128. Without this the
// allocator targeted max occupancy, clamped to 32 VGPRs and spilled the whole
// working set to scratch (r3/r4: +190MB WRITE_SIZE, 5x slowdown).
// NO ticket finalize: a per-block __threadfence (L2 writeback) + single-line
// atomic across 3088 blocks cost ~140us in r5. k_final is its own launch.
__global__ __launch_bounds__(256, 4) void k_main(
    const float* __restrict__ x, const float* __restrict__ targets,
    float* __restrict__ out, double* __restrict__ sums,
    int T, int G, float stride, int total_cells, int nblkT,
    const int* __restrict__ ocell, const int* __restrict__ keyarr,
    const int* __restrict__ A_key, const int* __restrict__ A_val,
    const int* __restrict__ B_key, const int* __restrict__ B_bits,
    const int* __restrict__ B_maxt)
{
  __shared__ double sred[4][12];
  int tid = threadIdx.x;
  int lane = tid & 63, wv = tid >> 6;

  if ((int)blockIdx.x < nblkT){
    // -------------------- sparse target path (precise math) --------------------
    int t = blockIdx.x*256 + tid;
    double v[12];
    #pragma unroll
    for (int k = 0; k < 12; ++k) v[k] = 0.0;
    // v: [0]=excl_nb [1]=excl_conf [2]=excl_cnt [3..6]=lx,ly,lw,lh
    //    [7]=bce [8]=conf_obj [9]=i50 [10]=i75 [11]=n_obj

    if (t < T){
      const float* tr = targets + (size_t)t*6;
      int b = (int)tr[0];
      float gx = tr[2]*(float)G, gy = tr[3]*(float)G, gw = tr[4]*(float)G, gh = tr[5]*(float)G;
      int okey = ocell[t];
      int myk  = keyarr[t];
      int cell = myk >> 3;
      int best = okey & 3;
      int gi = cell % G;
      int gj = (cell / G) % G;
      int GG = G*G;

      // ownership lookup (last target wins)
      unsigned s = hslot((unsigned)okey) & HMASK;
      while (A_key[s] != okey+1) s = (s+1) & HMASK;
      bool owner = (A_val[s] == t+1);

      if (owner){
        float awb = (best==0 ? 116.0f : (best==1 ? 156.0f : 373.0f)) / stride;
        float ahb = (best==0 ?  90.0f : (best==1 ? 198.0f : 326.0f)) / stride;
        const float* xp = x + ((size_t)(b*(NA*5) + best*5))*GG + (size_t)gj*G + gi;
        float x0 = xp[0], x1 = xp[(size_t)GG], x2 = xp[(size_t)2*GG],
              x3 = xp[(size_t)3*GG], x4 = xp[(size_t)4*GG];
        float cx = sigf(x0), cy = sigf(x1), w = x2, h = x3, conf = sigf(x4);
        float tx = gx - (float)gi, ty = gy - (float)gj;
        float tw = logf(gw/awb + 1e-16f), th = logf(gh/ahb + 1e-16f);
        v[3] = (double)((cx-tx)*(cx-tx));
        v[4] = (double)((cy-ty)*(cy-ty));
        v[5] = (double)((w-tw)*(w-tw));
        v[6] = (double)((h-th)*(h-th));
        v[7] = (double)(-logf(conf + 1e-12f));
        v[8] = (double)conf;
        float px = (float)gi + cx, py = (float)gj + cy;
        float pw = expf(w)*awb, ph = expf(h)*ahb;
        float iw = fminf(px + pw*0.5f, gx + gw*0.5f) - fmaxf(px - pw*0.5f, gx - gw*0.5f);
        float ih = fminf(py + ph*0.5f, gy + gh*0.5f) - fmaxf(py - ph*0.5f, gy - gh*0.5f);
        iw = fmaxf(iw, 0.0f); ih = fmaxf(ih, 0.0f);
        float inter = iw*ih;
        float iou = inter / (pw*ph + gw*gh - inter + 1e-16f);
        bool det = conf > 0.5f;
        v[9]  = (iou > 0.5f  && det) ? 1.0 : 0.0;
        v[10] = (iou > 0.75f && det) ? 1.0 : 0.0;
        v[11] = 1.0;
      }

      // exclusion: representative per distinct cell processes the bit union
      s = hslot((unsigned)cell) & HMASK;
      while (B_key[s] != cell+1) s = (s+1) & HMASK;
      if (B_maxt[s] == t+1){
        int bits = B_bits[s];
        #pragma unroll
        for (int a = 0; a < NA; ++a){
          if (bits & (1 << a)){
            float x4 = x[((size_t)(b*(NA*5) + a*5 + 4))*GG + (size_t)gj*G + gi];
            float conf = sigf(x4);
            v[0] += (double)(-logf(1.0f - conf + 1e-12f));
            v[1] += (double)conf;
            v[2] += 1.0;
          }
        }
      }
    }

    #pragma unroll
    for (int k = 0; k < 12; ++k){
      #pragma unroll
      for (int off = 32; off > 0; off >>= 1) v[k] += __shfl_down(v[k], off);
    }
    if (lane == 0){
      #pragma unroll
      for (int k = 0; k < 12; ++k) sred[wv][k] = v[k];
    }
    __syncthreads();
    if (tid < 12){
      double sm = sred[0][tid] + sred[1][tid] + sred[2][tid] + sred[3][tid];
      unsafeAtomicAdd(&sums[3 + tid], sm);
    }
  } else {
    // -------------------- dense path: 8 cells/thread, no LDS, no arrays ------
    int dblk = blockIdx.x - nblkT;
    int i = dblk*256 + tid;
    int cell = i*8;
    float nb = 0.0f, cs = 0.0f; int c50 = 0;

    if (cell < total_cells){
      int GG = G*G;
      int gx    = cell % G;           // multiple of 8
      int row   = cell / G;
      int gy    = row % G;
      int plane = row / G;            // b*3 + a
      int a     = plane % NA;
      float aw = (a==0 ? 116.0f : (a==1 ? 156.0f : 373.0f)) / stride;
      float ah = (a==0 ?  90.0f : (a==1 ? 198.0f : 326.0f)) / stride;

      const float* xb = x + (size_t)plane*5*GG + (size_t)gy*G + gx;
      // 10 named v4f loads — all issued before any compute (MLP)
      v4f pa0 = *(const v4f*)(xb);
      v4f pb0 = *(const v4f*)(xb + 4);
      v4f pa1 = *(const v4f*)(xb + (size_t)GG);
      v4f pb1 = *(const v4f*)(xb + (size_t)GG + 4);
      v4f pa2 = *(const v4f*)(xb + (size_t)2*GG);
      v4f pb2 = *(const v4f*)(xb + (size_t)2*GG + 4);
      v4f pa3 = *(const v4f*)(xb + (size_t)3*GG);
      v4f pb3 = *(const v4f*)(xb + (size_t)3*GG + 4);
      v4f pa4 = *(const v4f*)(xb + (size_t)4*GG);
      v4f pb4 = *(const v4f*)(xb + (size_t)4*GG + 4);

      // cell j fields f0..f4 -> output floats 5j..5j+4 ; qk covers 4k..4k+3
      v4f q0, q1, q2, q3, q4, q5, q6, q7, q8, q9;
      DO_CELL(0, pa0.x, pa1.x, pa2.x, pa3.x, pa4.x, q0.x, q0.y, q0.z, q0.w, q1.x)
      DO_CELL(1, pa0.y, pa1.y, pa2.y, pa3.y, pa4.y, q1.y, q1.z, q1.w, q2.x, q2.y)
      DO_CELL(2, pa0.z, pa1.z, pa2.z, pa3.z, pa4.z, q2.z, q2.w, q3.x, q3.y, q3.z)
      DO_CELL(3, pa0.w, pa1.w, pa2.w, pa3.w, pa4.w, q3.w, q4.x, q4.y, q4.z, q4.w)
      DO_CELL(4, pb0.x, pb1.x, pb2.x, pb3.x, pb4.x, q5.x, q5.y, q5.z, q5.w, q6.x)
      DO_CELL(5, pb0.y, pb1.y, pb2.y, pb3.y, pb4.y, q6.y, q6.z, q6.w, q7.x, q7.y)
      DO_CELL(6, pb0.z, pb1.z, pb2.z, pb3.z, pb4.z, q7.z, q7.w, q8.x, q8.y, q8.z)
      DO_CELL(7, pb0.w, pb1.w, pb2.w, pb3.w, pb4.w, q8.w, q9.x, q9.y, q9.z, q9.w)

      // 160B contiguous per thread, 16B-aligned (i*40 floats = i*160 bytes)
      v4f* ob = (v4f*)(out + (size_t)i*40);
      __builtin_nontemporal_store(q0, ob + 0);
      __builtin_nontemporal_store(q1, ob + 1);
      __builtin_nontemporal_store(q2, ob + 2);
      __builtin_nontemporal_store(q3, ob + 3);
      __builtin_nontemporal_store(q4, ob + 4);
      __builtin_nontemporal_store(q5, ob + 5);
      __builtin_nontemporal_store(q6, ob + 6);
      __builtin_nontemporal_store(q7, ob + 7);
      __builtin_nontemporal_store(q8, ob + 8);
      __builtin_nontemporal_store(q9, ob + 9);
    }

    float vals[3] = {nb, cs, (float)c50};
    #pragma unroll
    for (int k = 0; k < 3; ++k){
      #pragma unroll
      for (int off = 32; off > 0; off >>= 1) vals[k] += __shfl_down(vals[k], off);
    }
    if (lane == 0){
      sred[wv][0] = (double)vals[0];
      sred[wv][1] = (double)vals[1];
      sred[wv][2] = (double)vals[2];
    }
    __syncthreads();
    if (tid < 3){
      double sm = sred[0][tid] + sred[1][tid] + sred[2][tid] + sred[3][tid];
      unsafeAtomicAdd(&sums[tid], sm);
    }
  }
}

__global__ __launch_bounds__(64) void k_final(
    const double* __restrict__ sums, float* __restrict__ tail, double total_cells)
{
  if (threadIdx.x != 0) return;
  double nb_all = sums[0], conf_all = sums[1], c50_all = sums[2];
  double enb = sums[3], econf = sums[4], ecnt = sums[5];
  double lx = sums[6], ly = sums[7], lw = sums[8], lh = sums[9];
  double bce = sums[10], cobj = sums[11], i50 = sums[12], i75 = sums[13], nobj = sums[14];

  double dObj = fmax(nobj, 1.0);
  double n_noobj = total_cells - ecnt;
  double dNo  = fmax(n_noobj, 1.0);

  double loss_x = lx/dObj, loss_y = ly/dObj, loss_w = lw/dObj, loss_h = lh/dObj;
  double loss_bbox = loss_x + loss_y + loss_w + loss_h;
  double loss_conf_obj   = bce/dObj;
  double loss_conf_noobj = (nb_all - enb)/dNo;
  double loss_conf  = 100.0*loss_conf_obj + 1.0*loss_conf_noobj;
  double loss_layer = loss_bbox + loss_conf;
  double conf_obj   = cobj/dObj;
  double conf_noobj = (conf_all - econf)/dNo;
  double precision  = i50/(c50_all + 1e-16);
  double recall50   = i50/(nobj + 1e-16);
  double recall75   = i75/(nobj + 1e-16);

  tail[0]  = (float)loss_layer;
  tail[1]  = (float)loss_x;
  tail[2]  = (float)loss_y;
  tail[3]  = (float)loss_w;
  tail[4]  = (float)loss_h;
  tail[5]  = (float)loss_bbox;
  tail[6]  = (float)loss_conf;
  tail[7]  = (float)loss_layer;
  tail[8]  = (float)conf_obj;
  tail[9]  = (float)conf_noobj;
  tail[10] = (float)precision;
  tail[11] = (float)recall50;
  tail[12] = (float)recall75;
}

extern "C" void kernel_launch(void* const* d_in, const int* in_sizes, int n_in,
                              void* d_out, int out_size, void* d_ws, size_t ws_size,
                              hipStream_t stream) {
  const float* x       = (const float*)d_in[0];
  const float* targets = (const float*)d_in[1];
  float* out = (float*)d_out;

  const int B = 32;
  int GG = in_sizes[0] / (B * NA * 5);
  int G = (int)(sqrt((double)GG) + 0.5);
  int T = in_sizes[1] / 6;
  float stride = 2048.0f / (float)G;

  char* ws = (char*)d_ws;
  double* sums  = (double*)ws;
  int* A_key  = (int*)(ws + 128);
  int* A_val  = A_key + HSIZE;
  int* B_key  = A_val + HSIZE;
  int* B_bits = B_key + HSIZE;
  int* B_maxt = B_bits + HSIZE;
  int* ocell  = B_maxt + HSIZE;
  int* keyarr = ocell + T;

  int total_cells = B * NA * GG;            // 6,291,456
  int nzero = 32 + 5*HSIZE;                 // sums (as ints) + tables
  int nblkZ = (nzero + 255) / 256;
  int nblkT = (T + 255) / 256;
  int nblkD = (total_cells + 2047) / 2048;  // 3072 (8 cells/thread)
  int nblkTot = nblkT + nblkD;

  k_zero   <<<nblkZ, 256, 0, stream>>>((int*)ws, nzero);
  k_targets<<<nblkT, 256, 0, stream>>>(targets, T, G, stride, ocell, keyarr,
                                       A_key, A_val, B_key, B_bits, B_maxt);
  k_main   <<<nblkTot, 256, 0, stream>>>(x, targets, out, sums,
                                       T, G, stride, total_cells, nblkT,
                                       ocell, keyarr,
                                       A_key, A_val, B_key, B_bits, B_maxt);
  k_final  <<<1, 64, 0, stream>>>(sums, out + (size_t)total_cells*5, (double)total_cells);
}

// Round 7
// 438.299 us; speedup vs baseline: 1.0635x; 1.0635x over previous
//
#include <hip/hip_runtime.h>
#include <cmath>

#define NA 3
#define HSIZE 8192
#define HMASK (HSIZE - 1)

typedef float v4f __attribute__((ext_vector_type(4)));

// ws layout:
//   0:      double sums[16]     [0]=nb_dense [1]=conf_dense [2]=c50_dense
//                               [3]=excl_nb [4]=excl_conf [5]=excl_cnt
//                               [6..9]=lx,ly,lw,lh [10]=bce_obj [11]=conf_obj
//                               [12]=i50det [13]=i75det [14]=n_obj
//   128:    int A_key[8192]  A_val[8192]  B_key[8192]  B_bits[8192]  B_maxt[8192]
//   then:   int ocell[T]  keyarr[T]

__device__ __forceinline__ float sigf(float v){ return 1.0f/(1.0f + expf(-v)); }
// fast path: v_exp_f32 + v_rcp_f32 (~1ulp) — dense bulk only
__device__ __forceinline__ float fast_sig(float v){
  return __builtin_amdgcn_rcpf(1.0f + __expf(-v));
}
__device__ __forceinline__ unsigned hslot(unsigned key){
  return (key * 2654435761u) >> 19;   // top 13 bits -> [0, 8192)
}

__global__ __launch_bounds__(256) void k_zero(int* __restrict__ p, int n){
  int i = blockIdx.x*256 + threadIdx.x;
  if (i < n) p[i] = 0;
}

__global__ __launch_bounds__(256) void k_targets(
    const float* __restrict__ targets, int T, int G, float stride,
    int* __restrict__ ocell, int* __restrict__ keyarr,
    int* __restrict__ A_key, int* __restrict__ A_val,
    int* __restrict__ B_key, int* __restrict__ B_bits, int* __restrict__ B_maxt)
{
  int t = blockIdx.x*256 + threadIdx.x;
  if (t >= T) return;
  const float* tr = targets + (size_t)t*6;
  int b = (int)tr[0];
  float gx = tr[2]*(float)G, gy = tr[3]*(float)G, gw = tr[4]*(float)G, gh = tr[5]*(float)G;
  float aw[NA] = {116.0f/stride, 156.0f/stride, 373.0f/stride};
  float ah[NA] = { 90.0f/stride, 198.0f/stride, 326.0f/stride};
  float best_iou = -1.0f; int best = 0; int bits = 0;
  #pragma unroll
  for (int a = 0; a < NA; ++a){
    float inter = fminf(aw[a], gw) * fminf(ah[a], gh);
    float uni   = aw[a]*ah[a] + gw*gh - inter;
    float iou   = inter / (uni + 1e-16f);
    if (iou > best_iou){ best_iou = iou; best = a; }
    if (iou > 0.5f) bits |= (1 << a);
  }
  bits |= (1 << best);
  int gi = (int)floorf(gx); gi = gi < 0 ? 0 : (gi > G-1 ? G-1 : gi);
  int gj = (int)floorf(gy); gj = gj < 0 ? 0 : (gj > G-1 ? G-1 : gj);
  int cell = (b*G + gj)*G + gi;             // < 2^21
  int okey = cell*4 + best;
  ocell[t]  = okey;
  keyarr[t] = (cell << 3) | bits;

  // table A: (cell,best) -> max t (last target wins scatter semantics)
  unsigned s = hslot((unsigned)okey) & HMASK;
  for (;;){
    int prev = atomicCAS(&A_key[s], 0, okey+1);
    if (prev == 0 || prev == okey+1){ atomicMax(&A_val[s], t+1); break; }
    s = (s+1) & HMASK;
  }
  // table B: cell -> union of excluded anchor bits, representative = max t
  s = hslot((unsigned)cell) & HMASK;
  for (;;){
    int prev = atomicCAS(&B_key[s], 0, cell+1);
    if (prev == 0 || prev == cell+1){
      atomicOr(&B_bits[s], bits);
      atomicMax(&B_maxt[s], t+1);
      break;
    }
    s = (s+1) & HMASK;
  }
}

// Per-cell compute: all operands are named scalars / vector components,
// indices compile-time — nothing can be demoted to scratch.
#define DO_CELL(JV, P0, P1, P2, P3, P4, O0, O1, O2, O3, O4)        \
  {                                                                \
    float cx_   = fast_sig(P0);                                    \
    float cy_   = fast_sig(P1);                                    \
    float pw_   = __expf(P2)*aw;                                   \
    float ph_   = __expf(P3)*ah;                                   \
    float cf_   = fast_sig(P4);                                    \
    O0 = ((float)(gx + (JV)) + cx_)*stride;                        \
    O1 = ((float)gy + cy_)*stride;                                 \
    O2 = pw_*stride;                                               \
    O3 = ph_*stride;                                               \
    O4 = cf_;                                                      \
    nb -= __logf(1.0f - cf_ + 1e-12f);                             \
    cs += cf_;                                                     \
    c50 += (cf_ > 0.5f) ? 1 : 0;                                   \
  }

// Fused kernel:
//   blocks [0, nblkT)       : sparse per-target path (scheduled FIRST; its
//                             hash-probe/gather latency hides under dense work)
//   blocks [nblkT, nblkTot) : dense path, 8 cells/thread, NO LDS staging —
//                             named-register transpose into 10 v4f NT stores
//                             (160B/thread contiguous).
//
// LDS GOVERNOR: ldsgov+sred = exactly 40,960 B. Empirical law from 6 rounds:
// the backend budgets VGPRs from the LDS-capped max occupancy
// (42KB->3WG->VGPR 68 ok; 22KB->7WG->36 ok; 0.5KB->8 waves/EU->32 + total
// scratch spill, REGARDLESS of __launch_bounds__ 2nd arg, which it ignores
// for budgeting). 40KB caps at 4 WG/CU -> budget 512/4 = 128 VGPRs >= ~110
// demand -> no spill, and one more resident block than r0's 3.
// NO ticket finalize: per-block __threadfence + serialized atomic across
// 3088 blocks cost ~140us in r5. k_final is its own launch.
__global__ __launch_bounds__(256) void k_main(
    const float* __restrict__ x, const float* __restrict__ targets,
    float* __restrict__ out, double* __restrict__ sums,
    int T, int G, float stride, int total_cells, int nblkT,
    const int* __restrict__ ocell, const int* __restrict__ keyarr,
    const int* __restrict__ A_key, const int* __restrict__ A_val,
    const int* __restrict__ B_key, const int* __restrict__ B_bits,
    const int* __restrict__ B_maxt)
{
  __shared__ float ldsgov[10144];   // 40,576 B — occupancy governor (see above)
  __shared__ double sred[4][12];    //    384 B — total 40,960 B
  int tid = threadIdx.x;
  int lane = tid & 63, wv = tid >> 6;

  if ((int)blockIdx.x < nblkT){
    // -------------------- sparse target path (precise math) --------------------
    int t = blockIdx.x*256 + tid;
    double v[12];
    #pragma unroll
    for (int k = 0; k < 12; ++k) v[k] = 0.0;
    // v: [0]=excl_nb [1]=excl_conf [2]=excl_cnt [3..6]=lx,ly,lw,lh
    //    [7]=bce [8]=conf_obj [9]=i50 [10]=i75 [11]=n_obj

    if (t < T){
      const float* tr = targets + (size_t)t*6;
      int b = (int)tr[0];
      float gx = tr[2]*(float)G, gy = tr[3]*(float)G, gw = tr[4]*(float)G, gh = tr[5]*(float)G;
      int okey = ocell[t];
      int myk  = keyarr[t];
      int cell = myk >> 3;
      int best = okey & 3;
      int gi = cell % G;
      int gj = (cell / G) % G;
      int GG = G*G;

      // ownership lookup (last target wins)
      unsigned s = hslot((unsigned)okey) & HMASK;
      while (A_key[s] != okey+1) s = (s+1) & HMASK;
      bool owner = (A_val[s] == t+1);

      if (owner){
        float awb = (best==0 ? 116.0f : (best==1 ? 156.0f : 373.0f)) / stride;
        float ahb = (best==0 ?  90.0f : (best==1 ? 198.0f : 326.0f)) / stride;
        const float* xp = x + ((size_t)(b*(NA*5) + best*5))*GG + (size_t)gj*G + gi;
        float x0 = xp[0], x1 = xp[(size_t)GG], x2 = xp[(size_t)2*GG],
              x3 = xp[(size_t)3*GG], x4 = xp[(size_t)4*GG];
        float cx = sigf(x0), cy = sigf(x1), w = x2, h = x3, conf = sigf(x4);
        float tx = gx - (float)gi, ty = gy - (float)gj;
        float tw = logf(gw/awb + 1e-16f), th = logf(gh/ahb + 1e-16f);
        v[3] = (double)((cx-tx)*(cx-tx));
        v[4] = (double)((cy-ty)*(cy-ty));
        v[5] = (double)((w-tw)*(w-tw));
        v[6] = (double)((h-th)*(h-th));
        v[7] = (double)(-logf(conf + 1e-12f));
        v[8] = (double)conf;
        float px = (float)gi + cx, py = (float)gj + cy;
        float pw = expf(w)*awb, ph = expf(h)*ahb;
        float iw = fminf(px + pw*0.5f, gx + gw*0.5f) - fmaxf(px - pw*0.5f, gx - gw*0.5f);
        float ih = fminf(py + ph*0.5f, gy + gh*0.5f) - fmaxf(py - ph*0.5f, gy - gh*0.5f);
        iw = fmaxf(iw, 0.0f); ih = fmaxf(ih, 0.0f);
        float inter = iw*ih;
        float iou = inter / (pw*ph + gw*gh - inter + 1e-16f);
        bool det = conf > 0.5f;
        v[9]  = (iou > 0.5f  && det) ? 1.0 : 0.0;
        v[10] = (iou > 0.75f && det) ? 1.0 : 0.0;
        v[11] = 1.0;
      }

      // exclusion: representative per distinct cell processes the bit union
      s = hslot((unsigned)cell) & HMASK;
      while (B_key[s] != cell+1) s = (s+1) & HMASK;
      if (B_maxt[s] == t+1){
        int bits = B_bits[s];
        #pragma unroll
        for (int a = 0; a < NA; ++a){
          if (bits & (1 << a)){
            float x4 = x[((size_t)(b*(NA*5) + a*5 + 4))*GG + (size_t)gj*G + gi];
            float conf = sigf(x4);
            v[0] += (double)(-logf(1.0f - conf + 1e-12f));
            v[1] += (double)conf;
            v[2] += 1.0;
          }
        }
      }
    }

    #pragma unroll
    for (int k = 0; k < 12; ++k){
      #pragma unroll
      for (int off = 32; off > 0; off >>= 1) v[k] += __shfl_down(v[k], off);
    }
    if (lane == 0){
      #pragma unroll
      for (int k = 0; k < 12; ++k) sred[wv][k] = v[k];
    }
    __syncthreads();
    if (tid < 12){
      double sm = sred[0][tid] + sred[1][tid] + sred[2][tid] + sred[3][tid];
      unsafeAtomicAdd(&sums[3 + tid], sm);
    }
  } else {
    // -------------------- dense path: 8 cells/thread, no LDS, no arrays ------
    int dblk = blockIdx.x - nblkT;
    int i = dblk*256 + tid;
    int cell = i*8;
    float nb = 0.0f, cs = 0.0f; int c50 = 0;

    if (cell < total_cells){
      int GG = G*G;
      int gx    = cell % G;           // multiple of 8
      int row   = cell / G;
      int gy    = row % G;
      int plane = row / G;            // b*3 + a
      int a     = plane % NA;
      float aw = (a==0 ? 116.0f : (a==1 ? 156.0f : 373.0f)) / stride;
      float ah = (a==0 ?  90.0f : (a==1 ? 198.0f : 326.0f)) / stride;

      const float* xb = x + (size_t)plane*5*GG + (size_t)gy*G + gx;
      // 10 named v4f loads — all issued before any compute (MLP)
      v4f pa0 = *(const v4f*)(xb);
      v4f pb0 = *(const v4f*)(xb + 4);
      v4f pa1 = *(const v4f*)(xb + (size_t)GG);
      v4f pb1 = *(const v4f*)(xb + (size_t)GG + 4);
      v4f pa2 = *(const v4f*)(xb + (size_t)2*GG);
      v4f pb2 = *(const v4f*)(xb + (size_t)2*GG + 4);
      v4f pa3 = *(const v4f*)(xb + (size_t)3*GG);
      v4f pb3 = *(const v4f*)(xb + (size_t)3*GG + 4);
      v4f pa4 = *(const v4f*)(xb + (size_t)4*GG);
      v4f pb4 = *(const v4f*)(xb + (size_t)4*GG + 4);

      // cell j fields f0..f4 -> output floats 5j..5j+4 ; qk covers 4k..4k+3
      v4f q0, q1, q2, q3, q4, q5, q6, q7, q8, q9;
      DO_CELL(0, pa0.x, pa1.x, pa2.x, pa3.x, pa4.x, q0.x, q0.y, q0.z, q0.w, q1.x)
      DO_CELL(1, pa0.y, pa1.y, pa2.y, pa3.y, pa4.y, q1.y, q1.z, q1.w, q2.x, q2.y)
      DO_CELL(2, pa0.z, pa1.z, pa2.z, pa3.z, pa4.z, q2.z, q2.w, q3.x, q3.y, q3.z)
      DO_CELL(3, pa0.w, pa1.w, pa2.w, pa3.w, pa4.w, q3.w, q4.x, q4.y, q4.z, q4.w)
      DO_CELL(4, pb0.x, pb1.x, pb2.x, pb3.x, pb4.x, q5.x, q5.y, q5.z, q5.w, q6.x)
      DO_CELL(5, pb0.y, pb1.y, pb2.y, pb3.y, pb4.y, q6.y, q6.z, q6.w, q7.x, q7.y)
      DO_CELL(6, pb0.z, pb1.z, pb2.z, pb3.z, pb4.z, q7.z, q7.w, q8.x, q8.y, q8.z)
      DO_CELL(7, pb0.w, pb1.w, pb2.w, pb3.w, pb4.w, q8.w, q9.x, q9.y, q9.z, q9.w)

      // 160B contiguous per thread, 16B-aligned (i*40 floats = i*160 bytes)
      v4f* ob = (v4f*)(out + (size_t)i*40);
      __builtin_nontemporal_store(q0, ob + 0);
      __builtin_nontemporal_store(q1, ob + 1);
      __builtin_nontemporal_store(q2, ob + 2);
      __builtin_nontemporal_store(q3, ob + 3);
      __builtin_nontemporal_store(q4, ob + 4);
      __builtin_nontemporal_store(q5, ob + 5);
      __builtin_nontemporal_store(q6, ob + 6);
      __builtin_nontemporal_store(q7, ob + 7);
      __builtin_nontemporal_store(q8, ob + 8);
      __builtin_nontemporal_store(q9, ob + 9);
    }

    float vals[3] = {nb, cs, (float)c50};
    #pragma unroll
    for (int k = 0; k < 3; ++k){
      #pragma unroll
      for (int off = 32; off > 0; off >>= 1) vals[k] += __shfl_down(vals[k], off);
    }
    if (lane == 0){
      sred[wv][0] = (double)vals[0];
      sred[wv][1] = (double)vals[1];
      sred[wv][2] = (double)vals[2];
    }
    __syncthreads();
    if (tid < 3){
      double sm = sred[0][tid] + sred[1][tid] + sred[2][tid] + sred[3][tid];
      unsafeAtomicAdd(&sums[tid], sm);
    }
  }

  // keep-alive for the LDS governor: block-uniform branch on a runtime value
  // the compiler cannot fold (G is a kernel argument; never 0 in practice).
  if (__builtin_expect(G == 0, 0)){
    ldsgov[tid] = (float)tid;
    __syncthreads();
    out[tid] = ldsgov[255 - tid];
  }
}

__global__ __launch_bounds__(64) void k_final(
    const double* __restrict__ sums, float* __restrict__ tail, double total_cells)
{
  if (threadIdx.x != 0) return;
  double nb_all = sums[0], conf_all = sums[1], c50_all = sums[2];
  double enb = sums[3], econf = sums[4], ecnt = sums[5];
  double lx = sums[6], ly = sums[7], lw = sums[8], lh = sums[9];
  double bce = sums[10], cobj = sums[11], i50 = sums[12], i75 = sums[13], nobj = sums[14];

  double dObj = fmax(nobj, 1.0);
  double n_noobj = total_cells - ecnt;
  double dNo  = fmax(n_noobj, 1.0);

  double loss_x = lx/dObj, loss_y = ly/dObj, loss_w = lw/dObj, loss_h = lh/dObj;
  double loss_bbox = loss_x + loss_y + loss_w + loss_h;
  double loss_conf_obj   = bce/dObj;
  double loss_conf_noobj = (nb_all - enb)/dNo;
  double loss_conf  = 100.0*loss_conf_obj + 1.0*loss_conf_noobj;
  double loss_layer = loss_bbox + loss_conf;
  double conf_obj   = cobj/dObj;
  double conf_noobj = (conf_all - econf)/dNo;
  double precision  = i50/(c50_all + 1e-16);
  double recall50   = i50/(nobj + 1e-16);
  double recall75   = i75/(nobj + 1e-16);

  tail[0]  = (float)loss_layer;
  tail[1]  = (float)loss_x;
  tail[2]  = (float)loss_y;
  tail[3]  = (float)loss_w;
  tail[4]  = (float)loss_h;
  tail[5]  = (float)loss_bbox;
  tail[6]  = (float)loss_conf;
  tail[7]  = (float)loss_layer;
  tail[8]  = (float)conf_obj;
  tail[9]  = (float)conf_noobj;
  tail[10] = (float)precision;
  tail[11] = (float)recall50;
  tail[12] = (float)recall75;
}

extern "C" void kernel_launch(void* const* d_in, const int* in_sizes, int n_in,
                              void* d_out, int out_size, void* d_ws, size_t ws_size,
                              hipStream_t stream) {
  const float* x       = (const float*)d_in[0];
  const float* targets = (const float*)d_in[1];
  float* out = (float*)d_out;

  const int B = 32;
  int GG = in_sizes[0] / (B * NA * 5);
  int G = (int)(sqrt((double)GG) + 0.5);
  int T = in_sizes[1] / 6;
  float stride = 2048.0f / (float)G;

  char* ws = (char*)d_ws;
  double* sums  = (double*)ws;
  int* A_key  = (int*)(ws + 128);
  int* A_val  = A_key + HSIZE;
  int* B_key  = A_val + HSIZE;
  int* B_bits = B_key + HSIZE;
  int* B_maxt = B_bits + HSIZE;
  int* ocell  = B_maxt + HSIZE;
  int* keyarr = ocell + T;

  int total_cells = B * NA * GG;            // 6,291,456
  int nzero = 32 + 5*HSIZE;                 // sums (as ints) + tables
  int nblkZ = (nzero + 255) / 256;
  int nblkT = (T + 255) / 256;
  int nblkD = (total_cells + 2047) / 2048;  // 3072 (8 cells/thread)

  k_zero   <<<nblkZ, 256, 0, stream>>>((int*)ws, nzero);
  k_targets<<<nblkT, 256, 0, stream>>>(targets, T, G, stride, ocell, keyarr,
                                       A_key, A_val, B_key, B_bits, B_maxt);
  k_main   <<<nblkT + nblkD, 256, 0, stream>>>(x, targets, out, sums,
                                       T, G, stride, total_cells, nblkT,
                                       ocell, keyarr,
                                       A_key, A_val, B_key, B_bits, B_maxt);
  k_final  <<<1, 64, 0, stream>>>(sums, out + (size_t)total_cells*5, (double)total_cells);
}

// Round 8
// 241.730 us; speedup vs baseline: 1.9283x; 1.8132x over previous
//
#include <hip/hip_runtime.h>
#include <cmath>

#define NA 3
#define HSIZE 8192
#define HMASK (HSIZE - 1)

typedef float v4f __attribute__((ext_vector_type(4)));

// ws layout:
//   0:      double sums[16]     [0]=nb_dense [1]=conf_dense [2]=c50_dense
//                               [3]=excl_nb [4]=excl_conf [5]=excl_cnt
//                               [6..9]=lx,ly,lw,lh [10]=bce_obj [11]=conf_obj
//                               [12]=i50det [13]=i75det [14]=n_obj
//   128:    int A_key[8192]  A_val[8192]  B_key[8192]  B_bits[8192]  B_maxt[8192]
//   then:   int ocell[T]  keyarr[T]

__device__ __forceinline__ float sigf(float v){ return 1.0f/(1.0f + expf(-v)); }
// fast path: v_exp_f32 + v_rcp_f32 (~1ulp) — dense bulk only
__device__ __forceinline__ float fast_sig(float v){
  return __builtin_amdgcn_rcpf(1.0f + __expf(-v));
}
__device__ __forceinline__ unsigned hslot(unsigned key){
  return (key * 2654435761u) >> 19;   // top 13 bits -> [0, 8192)
}

__global__ __launch_bounds__(256) void k_zero(int* __restrict__ p, int n){
  int i = blockIdx.x*256 + threadIdx.x;
  if (i < n) p[i] = 0;
}

__global__ __launch_bounds__(256) void k_targets(
    const float* __restrict__ targets, int T, int G, float stride,
    int* __restrict__ ocell, int* __restrict__ keyarr,
    int* __restrict__ A_key, int* __restrict__ A_val,
    int* __restrict__ B_key, int* __restrict__ B_bits, int* __restrict__ B_maxt)
{
  int t = blockIdx.x*256 + threadIdx.x;
  if (t >= T) return;
  const float* tr = targets + (size_t)t*6;
  int b = (int)tr[0];
  float gx = tr[2]*(float)G, gy = tr[3]*(float)G, gw = tr[4]*(float)G, gh = tr[5]*(float)G;
  float aw[NA] = {116.0f/stride, 156.0f/stride, 373.0f/stride};
  float ah[NA] = { 90.0f/stride, 198.0f/stride, 326.0f/stride};
  float best_iou = -1.0f; int best = 0; int bits = 0;
  #pragma unroll
  for (int a = 0; a < NA; ++a){
    float inter = fminf(aw[a], gw) * fminf(ah[a], gh);
    float uni   = aw[a]*ah[a] + gw*gh - inter;
    float iou   = inter / (uni + 1e-16f);
    if (iou > best_iou){ best_iou = iou; best = a; }
    if (iou > 0.5f) bits |= (1 << a);
  }
  bits |= (1 << best);
  int gi = (int)floorf(gx); gi = gi < 0 ? 0 : (gi > G-1 ? G-1 : gi);
  int gj = (int)floorf(gy); gj = gj < 0 ? 0 : (gj > G-1 ? G-1 : gj);
  int cell = (b*G + gj)*G + gi;             // < 2^21
  int okey = cell*4 + best;
  ocell[t]  = okey;
  keyarr[t] = (cell << 3) | bits;

  // table A: (cell,best) -> max t (last target wins scatter semantics)
  unsigned s = hslot((unsigned)okey) & HMASK;
  for (;;){
    int prev = atomicCAS(&A_key[s], 0, okey+1);
    if (prev == 0 || prev == okey+1){ atomicMax(&A_val[s], t+1); break; }
    s = (s+1) & HMASK;
  }
  // table B: cell -> union of excluded anchor bits, representative = max t
  s = hslot((unsigned)cell) & HMASK;
  for (;;){
    int prev = atomicCAS(&B_key[s], 0, cell+1);
    if (prev == 0 || prev == cell+1){
      atomicOr(&B_bits[s], bits);
      atomicMax(&B_maxt[s], t+1);
      break;
    }
    s = (s+1) & HMASK;
  }
}

// Fused kernel = round-0 proven dense body + fast-math + fused sparse path.
//   blocks [0, nblkT)       : sparse per-target path (scheduled FIRST; its
//                             hash-probe/gather latency hides under dense work)
//   blocks [nblkT, ...)     : dense path — 8 cells/thread, planar v4f loads ->
//                             fast-math -> LDS stride-41 transpose -> per-wave
//                             LINE-COALESCED 1KB NT stores.
// WHY the LDS transpose is mandatory (r3/r4/r6/r7 evidence): per-thread
// 160B-strided NT stores write each 64B line via 4 separate instructions;
// NT retention flushes partial lines early -> WRITE_SIZE 316-446MB (2.5-3.6x).
// Per-wave coalesced stores fill whole lines per instruction -> exactly 123MB.
// WHY 42KB LDS: the allocator budgets VGPRs from LDS-capped occupancy
// (ignores __launch_bounds__ 2nd arg): 42KB -> 3 WG/CU -> VGPR 68, no spill
// (proven r0/r5). Small-LDS variants got budget-clamped to 32-52 and spilled.
// NO ticket finalize: per-block __threadfence + serialized atomic across all
// blocks cost ~140us (r5). k_final is its own ~3us launch.
__global__ __launch_bounds__(256) void k_main(
    const float* __restrict__ x, const float* __restrict__ targets,
    float* __restrict__ out, double* __restrict__ sums,
    int T, int G, float stride, int total_cells, int nblkT,
    const int* __restrict__ ocell, const int* __restrict__ keyarr,
    const int* __restrict__ A_key, const int* __restrict__ A_val,
    const int* __restrict__ B_key, const int* __restrict__ B_bits,
    const int* __restrict__ B_maxt)
{
  __shared__ float lds[256*41];   // 41,984 B — transpose buffer + VGPR governor
  __shared__ double sred[4][12];
  int tid = threadIdx.x;
  int lane = tid & 63, wv = tid >> 6;

  if ((int)blockIdx.x < nblkT){
    // -------------------- sparse target path (precise math) --------------------
    int t = blockIdx.x*256 + tid;
    double v[12];
    #pragma unroll
    for (int k = 0; k < 12; ++k) v[k] = 0.0;
    // v: [0]=excl_nb [1]=excl_conf [2]=excl_cnt [3..6]=lx,ly,lw,lh
    //    [7]=bce [8]=conf_obj [9]=i50 [10]=i75 [11]=n_obj

    if (t < T){
      const float* tr = targets + (size_t)t*6;
      int b = (int)tr[0];
      float gx = tr[2]*(float)G, gy = tr[3]*(float)G, gw = tr[4]*(float)G, gh = tr[5]*(float)G;
      int okey = ocell[t];
      int myk  = keyarr[t];
      int cell = myk >> 3;
      int best = okey & 3;
      int gi = cell % G;
      int gj = (cell / G) % G;
      int GG = G*G;

      // ownership lookup (last target wins)
      unsigned s = hslot((unsigned)okey) & HMASK;
      while (A_key[s] != okey+1) s = (s+1) & HMASK;
      bool owner = (A_val[s] == t+1);

      if (owner){
        float awb = (best==0 ? 116.0f : (best==1 ? 156.0f : 373.0f)) / stride;
        float ahb = (best==0 ?  90.0f : (best==1 ? 198.0f : 326.0f)) / stride;
        const float* xp = x + ((size_t)(b*(NA*5) + best*5))*GG + (size_t)gj*G + gi;
        float x0 = xp[0], x1 = xp[(size_t)GG], x2 = xp[(size_t)2*GG],
              x3 = xp[(size_t)3*GG], x4 = xp[(size_t)4*GG];
        float cx = sigf(x0), cy = sigf(x1), w = x2, h = x3, conf = sigf(x4);
        float tx = gx - (float)gi, ty = gy - (float)gj;
        float tw = logf(gw/awb + 1e-16f), th = logf(gh/ahb + 1e-16f);
        v[3] = (double)((cx-tx)*(cx-tx));
        v[4] = (double)((cy-ty)*(cy-ty));
        v[5] = (double)((w-tw)*(w-tw));
        v[6] = (double)((h-th)*(h-th));
        v[7] = (double)(-logf(conf + 1e-12f));
        v[8] = (double)conf;
        float px = (float)gi + cx, py = (float)gj + cy;
        float pw = expf(w)*awb, ph = expf(h)*ahb;
        float iw = fminf(px + pw*0.5f, gx + gw*0.5f) - fmaxf(px - pw*0.5f, gx - gw*0.5f);
        float ih = fminf(py + ph*0.5f, gy + gh*0.5f) - fmaxf(py - ph*0.5f, gy - gh*0.5f);
        iw = fmaxf(iw, 0.0f); ih = fmaxf(ih, 0.0f);
        float inter = iw*ih;
        float iou = inter / (pw*ph + gw*gh - inter + 1e-16f);
        bool det = conf > 0.5f;
        v[9]  = (iou > 0.5f  && det) ? 1.0 : 0.0;
        v[10] = (iou > 0.75f && det) ? 1.0 : 0.0;
        v[11] = 1.0;
      }

      // exclusion: representative per distinct cell processes the bit union
      s = hslot((unsigned)cell) & HMASK;
      while (B_key[s] != cell+1) s = (s+1) & HMASK;
      if (B_maxt[s] == t+1){
        int bits = B_bits[s];
        #pragma unroll
        for (int a = 0; a < NA; ++a){
          if (bits & (1 << a)){
            float x4 = x[((size_t)(b*(NA*5) + a*5 + 4))*GG + (size_t)gj*G + gi];
            float conf = sigf(x4);
            v[0] += (double)(-logf(1.0f - conf + 1e-12f));
            v[1] += (double)conf;
            v[2] += 1.0;
          }
        }
      }
    }

    #pragma unroll
    for (int k = 0; k < 12; ++k){
      #pragma unroll
      for (int off = 32; off > 0; off >>= 1) v[k] += __shfl_down(v[k], off);
    }
    if (lane == 0){
      #pragma unroll
      for (int k = 0; k < 12; ++k) sred[wv][k] = v[k];
    }
    __syncthreads();
    if (tid < 12){
      double sm = sred[0][tid] + sred[1][tid] + sred[2][tid] + sred[3][tid];
      unsafeAtomicAdd(&sums[3 + tid], sm);
    }
  } else {
    // ------------- dense path (r0 proven body + fast-math) -------------
    int dblk = blockIdx.x - nblkT;
    int i = dblk*256 + tid;
    int cell = i*8;
    float nb = 0.0f, cs = 0.0f; int c50 = 0;

    if (cell < total_cells){
      int GG = G*G;
      int gx    = cell % G;           // multiple of 8
      int row   = cell / G;
      int gy    = row % G;
      int plane = row / G;            // b*3 + a
      int a     = plane % NA;
      float aw = (a==0 ? 116.0f : (a==1 ? 156.0f : 373.0f)) / stride;
      float ah = (a==0 ?  90.0f : (a==1 ? 198.0f : 326.0f)) / stride;

      size_t base = (size_t)plane*5*GG + (size_t)gy*G + gx;
      v4f p[5][2];
      #pragma unroll
      for (int c = 0; c < 5; ++c){
        const v4f* pp = (const v4f*)(x + base + (size_t)c*GG);
        p[c][0] = pp[0];
        p[c][1] = pp[1];
      }

      float* myl = lds + tid*41;
      #pragma unroll
      for (int j = 0; j < 8; ++j){
        float cx   = fast_sig(p[0][j>>2][j&3]);
        float cy   = fast_sig(p[1][j>>2][j&3]);
        float pw   = __expf(p[2][j>>2][j&3])*aw;
        float ph   = __expf(p[3][j>>2][j&3])*ah;
        float conf = fast_sig(p[4][j>>2][j&3]);
        myl[j*5+0] = ((float)(gx + j) + cx)*stride;
        myl[j*5+1] = ((float)gy + cy)*stride;
        myl[j*5+2] = pw*stride;
        myl[j*5+3] = ph*stride;
        myl[j*5+4] = conf;
        nb -= __logf(1.0f - conf + 1e-12f);
        cs += conf;
        c50 += (conf > 0.5f) ? 1 : 0;
      }
    }
    __syncthreads();

    // store phase: wave wv owns output floats [waveBase, waveBase+2560)
    // each instruction: 64 lanes x 16B consecutive = 1KB -> full 64B lines.
    {
      size_t waveBase = ((size_t)dblk*2048 + (size_t)wv*512)*5;
      if (waveBase < (size_t)total_cells*5){
        const float* wl = lds + (size_t)(wv*64)*41;
        #pragma unroll
        for (int c = 0; c < 10; ++c){
          int f = (c*64 + lane)*4;        // [0, 2560)
          int owner = f / 40;
          int within = f - owner*40;
          const float* src = wl + owner*41 + within;
          v4f val;
          val.x = src[0]; val.y = src[1]; val.z = src[2]; val.w = src[3];
          __builtin_nontemporal_store(val, (v4f*)(out + waveBase + f));
        }
      }
    }

    float vals[3] = {nb, cs, (float)c50};
    #pragma unroll
    for (int k = 0; k < 3; ++k){
      #pragma unroll
      for (int off = 32; off > 0; off >>= 1) vals[k] += __shfl_down(vals[k], off);
    }
    if (lane == 0){
      sred[wv][0] = (double)vals[0];
      sred[wv][1] = (double)vals[1];
      sred[wv][2] = (double)vals[2];
    }
    __syncthreads();
    if (tid < 3){
      double sm = sred[0][tid] + sred[1][tid] + sred[2][tid] + sred[3][tid];
      unsafeAtomicAdd(&sums[tid], sm);
    }
  }
}

__global__ __launch_bounds__(64) void k_final(
    const double* __restrict__ sums, float* __restrict__ tail, double total_cells)
{
  if (threadIdx.x != 0) return;
  double nb_all = sums[0], conf_all = sums[1], c50_all = sums[2];
  double enb = sums[3], econf = sums[4], ecnt = sums[5];
  double lx = sums[6], ly = sums[7], lw = sums[8], lh = sums[9];
  double bce = sums[10], cobj = sums[11], i50 = sums[12], i75 = sums[13], nobj = sums[14];

  double dObj = fmax(nobj, 1.0);
  double n_noobj = total_cells - ecnt;
  double dNo  = fmax(n_noobj, 1.0);

  double loss_x = lx/dObj, loss_y = ly/dObj, loss_w = lw/dObj, loss_h = lh/dObj;
  double loss_bbox = loss_x + loss_y + loss_w + loss_h;
  double loss_conf_obj   = bce/dObj;
  double loss_conf_noobj = (nb_all - enb)/dNo;
  double loss_conf  = 100.0*loss_conf_obj + 1.0*loss_conf_noobj;
  double loss_layer = loss_bbox + loss_conf;
  double conf_obj   = cobj/dObj;
  double conf_noobj = (conf_all - econf)/dNo;
  double precision  = i50/(c50_all + 1e-16);
  double recall50   = i50/(nobj + 1e-16);
  double recall75   = i75/(nobj + 1e-16);

  tail[0]  = (float)loss_layer;
  tail[1]  = (float)loss_x;
  tail[2]  = (float)loss_y;
  tail[3]  = (float)loss_w;
  tail[4]  = (float)loss_h;
  tail[5]  = (float)loss_bbox;
  tail[6]  = (float)loss_conf;
  tail[7]  = (float)loss_layer;
  tail[8]  = (float)conf_obj;
  tail[9]  = (float)conf_noobj;
  tail[10] = (float)precision;
  tail[11] = (float)recall50;
  tail[12] = (float)recall75;
}

extern "C" void kernel_launch(void* const* d_in, const int* in_sizes, int n_in,
                              void* d_out, int out_size, void* d_ws, size_t ws_size,
                              hipStream_t stream) {
  const float* x       = (const float*)d_in[0];
  const float* targets = (const float*)d_in[1];
  float* out = (float*)d_out;

  const int B = 32;
  int GG = in_sizes[0] / (B * NA * 5);
  int G = (int)(sqrt((double)GG) + 0.5);
  int T = in_sizes[1] / 6;
  float stride = 2048.0f / (float)G;

  char* ws = (char*)d_ws;
  double* sums  = (double*)ws;
  int* A_key  = (int*)(ws + 128);
  int* A_val  = A_key + HSIZE;
  int* B_key  = A_val + HSIZE;
  int* B_bits = B_key + HSIZE;
  int* B_maxt = B_bits + HSIZE;
  int* ocell  = B_maxt + HSIZE;
  int* keyarr = ocell + T;

  int total_cells = B * NA * GG;            // 6,291,456
  int nzero = 32 + 5*HSIZE;                 // sums (as ints) + tables
  int nblkZ = (nzero + 255) / 256;
  int nblkT = (T + 255) / 256;
  int nblkD = (total_cells + 2047) / 2048;  // 3072 (8 cells/thread)

  k_zero   <<<nblkZ, 256, 0, stream>>>((int*)ws, nzero);
  k_targets<<<nblkT, 256, 0, stream>>>(targets, T, G, stride, ocell, keyarr,
                                       A_key, A_val, B_key, B_bits, B_maxt);
  k_main   <<<nblkT + nblkD, 256, 0, stream>>>(x, targets, out, sums,
                                       T, G, stride, total_cells, nblkT,
                                       ocell, keyarr,
                                       A_key, A_val, B_key, B_bits, B_maxt);
  k_final  <<<1, 64, 0, stream>>>(sums, out + (size_t)total_cells*5, (double)total_cells);
}